// Round 3
// baseline (14537.079 us; speedup 1.0000x reference)
//
#include <hip/hip_runtime.h>

#define TT 256
#define BB 64
#define DD 1024
#define HH 1024
#define BH (BB * HH)              // 65536
#define TBH ((size_t)TT * BB * HH)

typedef short bf16x8 __attribute__((ext_vector_type(8)));
typedef float floatx4 __attribute__((ext_vector_type(4)));

__device__ __forceinline__ unsigned short f2bf(float f) {
  union { float f; unsigned u; } v; v.f = f;
  unsigned r = v.u + 0x7FFFu + ((v.u >> 16) & 1u);   // RNE
  return (unsigned short)(r >> 16);
}
__device__ __forceinline__ bf16x8 cvt8(float4 a, float4 b) {
  bf16x8 r;
  r[0]=(short)f2bf(a.x); r[1]=(short)f2bf(a.y); r[2]=(short)f2bf(a.z); r[3]=(short)f2bf(a.w);
  r[4]=(short)f2bf(b.x); r[5]=(short)f2bf(b.y); r[6]=(short)f2bf(b.z); r[7]=(short)f2bf(b.w);
  return r;
}
__device__ __forceinline__ float sigmoid_(float x) { return 1.f / (1.f + __expf(-x)); }

// ---- Phase A0: convert x and the x-half of W to bf16
__global__ void cvt_kernel(const float* __restrict__ x,
                           const float* __restrict__ Wf, const float* __restrict__ Wi,
                           const float* __restrict__ Wg, const float* __restrict__ Wo,
                           unsigned short* __restrict__ xbf,
                           unsigned short* __restrict__ wxbf) {  // [4][1024][1024]
  int i = (blockIdx.x * blockDim.x + threadIdx.x) * 4;
  int stride = gridDim.x * blockDim.x * 4;
  int n_x = TT * BB * DD;
  for (int p = i; p < n_x; p += stride) {
    float4 f = *(const float4*)(x + p);
    ushort4 u; u.x=f2bf(f.x); u.y=f2bf(f.y); u.z=f2bf(f.z); u.w=f2bf(f.w);
    *(ushort4*)(xbf + p) = u;
  }
  const float* Ws[4] = {Wf, Wi, Wg, Wo};
  for (int g = 0; g < 4; ++g) {
    const float* W = Ws[g];
    unsigned short* dst = wxbf + ((size_t)g << 20);
    for (int p = i; p < (1 << 20); p += stride) {
      int row = p >> 10, k = p & 1023;
      float4 f = *(const float4*)(W + (size_t)row * 2048 + k);
      ushort4 u; u.x=f2bf(f.x); u.y=f2bf(f.y); u.z=f2bf(f.z); u.w=f2bf(f.w);
      *(ushort4*)(dst + p) = u;
    }
  }
}

// ---- Phase A1: zx[16384][4096] = xbf @ WxT + b  (time-parallel GEMM)
__global__ void __launch_bounds__(256, 1)
zx_gemm(const unsigned short* __restrict__ xbf, const unsigned short* __restrict__ wxbf,
        const float* __restrict__ bfp, const float* __restrict__ bip,
        const float* __restrict__ bgp, const float* __restrict__ bop,
        float* __restrict__ zx) {
  extern __shared__ unsigned short wlds[];   // 64 cols * 1024 k bf16 = 128 KB
  const int tid = threadIdx.x;
  const int cg = blockIdx.x & 63;            // 64 col-groups (16 h-cols each)
  const int mg = blockIdx.x >> 6;            // 16 row-groups (1024 rows each)

  for (int g = 0; g < 4; ++g) {
    for (int it = 0; it < 8; ++it) {
      int idx = it * 256 + tid;              // 0..2047
      int colg = idx >> 7;                   // 0..15
      int k = (idx & 127) * 8;
      int col = g * 16 + colg;
      bf16x8 w = *(const bf16x8*)(wxbf + (((size_t)g << 20) | ((size_t)(cg * 16 + colg) << 10) | k));
      *(bf16x8*)&wlds[col * 1024 + (k ^ ((col & 7) * 8))] = w;
    }
  }
  __syncthreads();

  const int lane = tid & 63, wave = tid >> 6;
  const int quad = lane >> 4, lcol = lane & 15;
  const int kq = quad * 8;
  const int colb = cg * 16 + lcol;
  float bias[4] = {bfp[colb], bip[colb], bgp[colb], bop[colb]};

  for (int mt = wave * 16; mt < wave * 16 + 16; ++mt) {
    const unsigned short* arow = xbf + (size_t)(mg * 1024 + mt * 16 + lcol) * DD;
    floatx4 acc[4] = {};
    #pragma unroll 4
    for (int ks = 0; ks < 32; ++ks) {
      int koff = ks * 32 + kq;
      bf16x8 a = *(const bf16x8*)(arow + koff);
      #pragma unroll
      for (int g = 0; g < 4; ++g) {
        int j = g * 16 + lcol;
        bf16x8 b = *(const bf16x8*)&wlds[j * 1024 + (koff ^ ((j & 7) * 8))];
        acc[g] = __builtin_amdgcn_mfma_f32_16x16x32_bf16(a, b, acc[g], 0, 0, 0);
      }
    }
    int rbase = mg * 1024 + mt * 16 + quad * 4;
    #pragma unroll
    for (int g = 0; g < 4; ++g)
      #pragma unroll
      for (int r = 0; r < 4; ++r)
        zx[(size_t)(rbase + r) * 4096 + g * 1024 + cg * 16 + lcol] = acc[g][r] + bias[g];
  }
}

// ---- Phase B: persistent recurrent loop. 64 wgs x 256 thr; wg owns 16 h-cols
// (4 gate N-tiles). Wh in LDS (128 KB). h exchanged via agent-coherent atomics,
// per-wave flag barrier, NO cache-invalidating fences.
__global__ void __launch_bounds__(256, 1)
lstm_rec(const float* __restrict__ x,
         const float* __restrict__ Wf, const float* __restrict__ bfp,
         const float* __restrict__ Wi, const float* __restrict__ bip,
         const float* __restrict__ Wg, const float* __restrict__ bgp,
         const float* __restrict__ Wo, const float* __restrict__ bop,
         float* __restrict__ out,
         unsigned short* __restrict__ hb,   // [2][B][H] bf16
         int* __restrict__ flags,           // [256 waves] stride 16 ints
         const float* __restrict__ zx,
         int mode)                           // 1 = zx precomputed, 3 = inline x
{
  extern __shared__ unsigned short wlds[];   // 64 cols * 1024 k = 128 KB (Wh)
  const int tid = threadIdx.x;
  const int wg  = blockIdx.x;                // 64 wgs

  const float* Ws[4] = {Wf, Wi, Wg, Wo};
  for (int g = 0; g < 4; ++g) {
    const float* W = Ws[g];
    for (int it = 0; it < 8; ++it) {
      int idx = it * 256 + tid;
      int colg = idx >> 7;
      int k = (idx & 127) * 8;
      int col = g * 16 + colg;
      const float* src = W + (size_t)(wg * 16 + colg) * 2048 + 1024 + k;
      float4 f0 = *(const float4*)src;
      float4 f1 = *(const float4*)(src + 4);
      *(bf16x8*)&wlds[col * 1024 + (k ^ ((col & 7) * 8))] = cvt8(f0, f1);
    }
  }
  // zero h buffer 0 coherently (16384 threads x one u64)
  {
    int gid = wg * 256 + tid;
    __hip_atomic_store((unsigned long long*)hb + gid, 0ULL,
                       __ATOMIC_RELAXED, __HIP_MEMORY_SCOPE_AGENT);
  }
  const int lane = tid & 63, wave = tid >> 6;
  const int wflag = wg * 4 + wave;
  asm volatile("s_waitcnt vmcnt(0)" ::: "memory");
  if (lane == 0)
    __hip_atomic_store(&flags[wflag * 16], 1, __ATOMIC_RELAXED, __HIP_MEMORY_SCOPE_AGENT);
  __syncthreads();   // LDS staging complete

  const int quad = lane >> 4, lcol = lane & 15;
  const int kq = quad * 8;
  const int m_row = wave * 16 + lcol;        // A-fragment batch row
  const int hcol = wg * 16 + lcol;           // this lane's h column
  const int row_e = wave * 16 + quad * 4;    // C row base
  float bias[4] = {bfp[hcol], bip[hcol], bgp[hcol], bop[hcol]};
  float creg[4] = {0.f, 0.f, 0.f, 0.f};
  const int f0i = lane, f1i = lane + 64, f2i = lane + 128, f3i = lane + 192;

  for (int t = 0; t < TT; ++t) {
    floatx4 acc[4] = {};
    float zxv[4][4];

    if (mode == 1) {
      // prefetch zx (no h dependence) before the barrier
      #pragma unroll
      for (int g = 0; g < 4; ++g)
        #pragma unroll
        for (int r = 0; r < 4; ++r)
          zxv[g][r] = zx[(size_t)(t * 64 + row_e + r) * 4096 + g * 1024 + hcol];
    } else {
      // inline x-half: A from x fp32, B from W fp32 (L2-resident; no invalidates)
      const float* xrow = x + ((size_t)t * BB + m_row) * DD;
      #pragma unroll 2
      for (int ks = 0; ks < 32; ++ks) {
        int koff = ks * 32 + kq;
        float4 f0 = *(const float4*)(xrow + koff);
        float4 f1 = *(const float4*)(xrow + koff + 4);
        bf16x8 a = cvt8(f0, f1);
        #pragma unroll
        for (int g = 0; g < 4; ++g) {
          const float* wsrc = Ws[g] + (size_t)hcol * 2048 + koff;
          float4 w0 = *(const float4*)wsrc;
          float4 w1 = *(const float4*)(wsrc + 4);
          acc[g] = __builtin_amdgcn_mfma_f32_16x16x32_bf16(a, cvt8(w0, w1), acc[g], 0, 0, 0);
        }
      }
      #pragma unroll
      for (int g = 0; g < 4; ++g)
        #pragma unroll
        for (int r = 0; r < 4; ++r) zxv[g][r] = bias[g];
    }

    // ---- spin barrier: wait all 256 waves past step t-1 (flags > t)
    while (true) {
      int a = __hip_atomic_load(&flags[f0i * 16], __ATOMIC_RELAXED, __HIP_MEMORY_SCOPE_AGENT);
      int b = __hip_atomic_load(&flags[f1i * 16], __ATOMIC_RELAXED, __HIP_MEMORY_SCOPE_AGENT);
      int c = __hip_atomic_load(&flags[f2i * 16], __ATOMIC_RELAXED, __HIP_MEMORY_SCOPE_AGENT);
      int d = __hip_atomic_load(&flags[f3i * 16], __ATOMIC_RELAXED, __HIP_MEMORY_SCOPE_AGENT);
      if (__all((a > t) && (b > t) && (c > t) && (d > t))) break;
      __builtin_amdgcn_s_sleep(1);
    }
    asm volatile("" ::: "memory");

    // ---- h half: A via coherent u64 loads, B from LDS
    const unsigned short* hrow = hb + (t & 1) * BH + m_row * HH;
    #pragma unroll 8
    for (int ks = 0; ks < 32; ++ks) {
      int koff = ks * 32 + kq;
      union { unsigned long long q[2]; bf16x8 v; } u;
      u.q[0] = __hip_atomic_load((const unsigned long long*)(hrow + koff),
                                 __ATOMIC_RELAXED, __HIP_MEMORY_SCOPE_AGENT);
      u.q[1] = __hip_atomic_load((const unsigned long long*)(hrow + koff + 4),
                                 __ATOMIC_RELAXED, __HIP_MEMORY_SCOPE_AGENT);
      #pragma unroll
      for (int g = 0; g < 4; ++g) {
        int j = g * 16 + lcol;
        bf16x8 b = *(const bf16x8*)&wlds[j * 1024 + (koff ^ ((j & 7) * 8))];
        acc[g] = __builtin_amdgcn_mfma_f32_16x16x32_bf16(u.v, b, acc[g], 0, 0, 0);
      }
    }

    // ---- epilogue: all 4 gates live in this lane; no shuffles
    unsigned short* hnext = hb + ((t + 1) & 1) * BH;
    #pragma unroll
    for (int r = 0; r < 4; ++r) {
      int row = row_e + r;
      float zf = acc[0][r] + zxv[0][r];
      float zi = acc[1][r] + zxv[1][r];
      float zg = acc[2][r] + zxv[2][r];
      float zo = acc[3][r] + zxv[3][r];
      float fv = sigmoid_(zf), iv = sigmoid_(zi), gv = tanhf(zg), ov = sigmoid_(zo);
      float cn = fv * creg[r] + iv * gv;
      float hn = ov * tanhf(cn);
      creg[r] = cn;
      int idx = row * HH + hcol;
      __hip_atomic_store(&hnext[idx], f2bf(hn), __ATOMIC_RELAXED, __HIP_MEMORY_SCOPE_AGENT);
      out[(size_t)t * BH + idx] = hn;
      if (t == TT - 1) { out[TBH + idx] = hn; out[TBH + BH + idx] = cn; }
    }

    if (t < TT - 1) {
      asm volatile("s_waitcnt vmcnt(0)" ::: "memory");   // h stores at LLC
      if (lane == 0)
        __hip_atomic_store(&flags[wflag * 16], t + 2, __ATOMIC_RELAXED, __HIP_MEMORY_SCOPE_AGENT);
    }
  }
}

extern "C" void kernel_launch(void* const* d_in, const int* in_sizes, int n_in,
                              void* d_out, int out_size, void* d_ws, size_t ws_size,
                              hipStream_t stream) {
  (void)in_sizes; (void)n_in; (void)out_size;
  const float* x   = (const float*)d_in[0];
  const float* Wf  = (const float*)d_in[1];
  const float* bfp = (const float*)d_in[2];
  const float* Wi  = (const float*)d_in[3];
  const float* bip = (const float*)d_in[4];
  const float* Wg  = (const float*)d_in[5];
  const float* bgp = (const float*)d_in[6];
  const float* Wo  = (const float*)d_in[7];
  const float* bop = (const float*)d_in[8];
  float* out = (float*)d_out;

  unsigned short* hb  = (unsigned short*)d_ws;                        // 256 KB
  int* flags          = (int*)((char*)d_ws + 262144);                 // 16 KB
  float* zx           = (float*)((char*)d_ws + 278528);               // 268.4 MB
  unsigned short* xbf = (unsigned short*)((char*)d_ws + 278528 + 268435456);            // 33.6 MB
  unsigned short* wxbf= (unsigned short*)((char*)d_ws + 278528 + 268435456 + 33554432); // 8.4 MB

  size_t need1 = 278528ULL + 268435456ULL + 33554432ULL + 8388608ULL;
  int mode = (ws_size >= need1) ? 1 : 3;

  hipFuncSetAttribute((const void*)zx_gemm, hipFuncAttributeMaxDynamicSharedMemorySize, 131072);
  hipFuncSetAttribute((const void*)lstm_rec, hipFuncAttributeMaxDynamicSharedMemorySize, 131072);

  if (mode == 1) {
    cvt_kernel<<<1024, 256, 0, stream>>>(x, Wf, Wi, Wg, Wo, xbf, wxbf);
    zx_gemm<<<dim3(1024), dim3(256), 131072, stream>>>(xbf, wxbf, bfp, bip, bgp, bop, zx);
  }
  void* args[] = { (void*)&x, (void*)&Wf, (void*)&bfp, (void*)&Wi, (void*)&bip,
                   (void*)&Wg, (void*)&bgp, (void*)&Wo, (void*)&bop,
                   (void*)&out, (void*)&hb, (void*)&flags, (void*)&zx, (void*)&mode };
  hipLaunchCooperativeKernel((void*)lstm_rec, dim3(64), dim3(256), args, 131072, stream);
}

// Round 5
// 4246.910 us; speedup vs baseline: 3.4230x; 3.4230x over previous
//
#include <hip/hip_runtime.h>

#define TT 256
#define BB 64
#define DD 1024
#define HH 1024
#define KTOT 2048                 // D + H
#define NWG 256                   // 256 wgs x 4 h-cols (16 gate-cols) each
#define BH (BB * HH)              // 65536
#define TBH ((size_t)TT * BB * HH)

typedef short bf16x8 __attribute__((ext_vector_type(8)));
typedef float floatx4 __attribute__((ext_vector_type(4)));

static __device__ __forceinline__ unsigned short f2bf(float f) {
  union { float f; unsigned u; } v; v.f = f;
  unsigned r = v.u + 0x7FFFu + ((v.u >> 16) & 1u);   // RNE
  return (unsigned short)(r >> 16);
}
static __device__ __forceinline__ bf16x8 cvt8(float4 a, float4 b) {
  bf16x8 r;
  r[0]=(short)f2bf(a.x); r[1]=(short)f2bf(a.y); r[2]=(short)f2bf(a.z); r[3]=(short)f2bf(a.w);
  r[4]=(short)f2bf(b.x); r[5]=(short)f2bf(b.y); r[6]=(short)f2bf(b.z); r[7]=(short)f2bf(b.w);
  return r;
}
static __device__ __forceinline__ float sigmoid_(float x) { return 1.f / (1.f + __expf(-x)); }

__global__ void cvt_x_kernel(const float* __restrict__ x, unsigned short* __restrict__ xb, int n) {
  int i = (blockIdx.x * blockDim.x + threadIdx.x) * 4;
  int stride = gridDim.x * blockDim.x * 4;
  for (; i < n; i += stride) {
    float4 f = *(const float4*)(x + i);
    ushort4 u;
    u.x = f2bf(f.x); u.y = f2bf(f.y); u.z = f2bf(f.z); u.w = f2bf(f.w);
    *(ushort4*)(xb + i) = u;
  }
}

// Persistent LSTM, 256 wgs x 256 thr. Full-K weights (16 gate-cols) in 64 KB
// LDS. Per step: x-half GEMM (pre-barrier, hides spin) -> flag-barrier ->
// h-half: 64 batched coherent u64 loads (issue loop separate from consume
// loop -> back-to-back global_load + fine-grained vmcnt) -> epilogue ->
// vmcnt drain -> flag. No fences, no L2 invalidation anywhere.
__global__ void __launch_bounds__(256, 1)
lstm_rec(const float* __restrict__ x,
         const float* __restrict__ Wf, const float* __restrict__ bfp,
         const float* __restrict__ Wi, const float* __restrict__ bip,
         const float* __restrict__ Wg, const float* __restrict__ bgp,
         const float* __restrict__ Wo, const float* __restrict__ bop,
         float* __restrict__ out,
         unsigned short* __restrict__ hb,   // [2][B][H] bf16 double buffer
         int* __restrict__ flags,           // [NWG] stride-16 ints
         const unsigned short* __restrict__ xbf,
         int use_xbf)
{
  extern __shared__ unsigned short wlds[];   // 16 * 2048 bf16 = 64 KB
  const int tid  = threadIdx.x;
  const int wg   = blockIdx.x;
  const int lane = tid & 63;
  const int wave = tid >> 6;
  const int quad = lane >> 4;
  const int lcol = lane & 15;
  const int gate = lcol >> 2;
  const int hc   = lcol & 3;

  // ---- stage 16 weight columns (full K=2048) into LDS, XOR-swizzled
  {
    int k = tid * 8;
    #pragma unroll
    for (int i = 0; i < 16; ++i) {
      int g = i >> 2;
      const float* W = (g == 0) ? Wf : (g == 1) ? Wi : (g == 2) ? Wg : Wo;
      const float* src = W + (size_t)(wg * 4 + (i & 3)) * KTOT + k;
      float4 f0 = *(const float4*)src;
      float4 f1 = *(const float4*)(src + 4);
      *(bf16x8*)&wlds[i * KTOT + (k ^ ((i & 7) * 8))] = cvt8(f0, f1);
    }
  }

  // ---- zero h buffer 0 ONLY (128 KB = 16384 u64): wgs 0..63, coherent stores
  if (wg < 64) {
    __hip_atomic_store((unsigned long long*)hb + wg * 256 + tid, 0ULL,
                       __ATOMIC_RELAXED, __HIP_MEMORY_SCOPE_AGENT);
  }
  asm volatile("s_waitcnt vmcnt(0)" ::: "memory");
  __syncthreads();
  if (tid == 0)
    __hip_atomic_store(&flags[wg * 16], 1, __ATOMIC_RELAXED, __HIP_MEMORY_SCOPE_AGENT);

  const int m_row = wave * 16 + lcol;        // A-fragment batch row
  const int kq = quad * 8;
  const float* bsel = (gate == 0) ? bfp : (gate == 1) ? bip : (gate == 2) ? bgp : bop;
  const float bias = bsel[wg * 4 + hc];
  const int row_e = wave * 16 + quad * 4;    // C row base
  const int col_e = wg * 4 + hc;             // global h column
  float creg[4] = {0.f, 0.f, 0.f, 0.f};

  for (int t = 0; t < TT; ++t) {
    // ---- x half (independent of h): compute BEFORE the barrier
    floatx4 ax0 = {0.f,0.f,0.f,0.f}, ax1 = {0.f,0.f,0.f,0.f};
    if (use_xbf) {
      const unsigned short* xbrow = xbf + ((size_t)t * BB + m_row) * DD;
      #pragma unroll 8
      for (int ks = 0; ks < 32; ++ks) {
        int koff = ks * 32 + kq;
        bf16x8 a = *(const bf16x8*)(xbrow + koff);
        bf16x8 b = *(const bf16x8*)&wlds[lcol * KTOT + (koff ^ ((lcol & 7) * 8))];
        if (ks & 1) ax1 = __builtin_amdgcn_mfma_f32_16x16x32_bf16(a, b, ax1, 0, 0, 0);
        else        ax0 = __builtin_amdgcn_mfma_f32_16x16x32_bf16(a, b, ax0, 0, 0, 0);
      }
    } else {
      const float* xrow = x + ((size_t)t * BB + m_row) * DD;
      #pragma unroll 4
      for (int ks = 0; ks < 32; ++ks) {
        int koff = ks * 32 + kq;
        float4 f0 = *(const float4*)(xrow + koff);
        float4 f1 = *(const float4*)(xrow + koff + 4);
        bf16x8 a = cvt8(f0, f1);
        bf16x8 b = *(const bf16x8*)&wlds[lcol * KTOT + (koff ^ ((lcol & 7) * 8))];
        if (ks & 1) ax1 = __builtin_amdgcn_mfma_f32_16x16x32_bf16(a, b, ax1, 0, 0, 0);
        else        ax0 = __builtin_amdgcn_mfma_f32_16x16x32_bf16(a, b, ax0, 0, 0, 0);
      }
    }

    // ---- barrier: wave 0 polls all 256 wg flags, others park at syncthreads
    if (tid < 64) {
      while (true) {
        int a = __hip_atomic_load(&flags[lane * 16],        __ATOMIC_RELAXED, __HIP_MEMORY_SCOPE_AGENT);
        int b = __hip_atomic_load(&flags[(lane + 64) * 16], __ATOMIC_RELAXED, __HIP_MEMORY_SCOPE_AGENT);
        int c = __hip_atomic_load(&flags[(lane + 128) * 16],__ATOMIC_RELAXED, __HIP_MEMORY_SCOPE_AGENT);
        int d = __hip_atomic_load(&flags[(lane + 192) * 16],__ATOMIC_RELAXED, __HIP_MEMORY_SCOPE_AGENT);
        if (__all((a > t) && (b > t) && (c > t) && (d > t))) break;
        __builtin_amdgcn_s_sleep(1);
      }
    }
    __syncthreads();

    // ---- h half: batch-issue 64 coherent u64 loads, then consume
    const unsigned short* hrow = hb + (t & 1) * BH + m_row * HH;
    unsigned long long hq[64];
    #pragma unroll
    for (int ks = 0; ks < 32; ++ks) {
      const unsigned short* ap = hrow + ks * 32 + kq;
      hq[2 * ks]     = __hip_atomic_load((const unsigned long long*)ap,
                                         __ATOMIC_RELAXED, __HIP_MEMORY_SCOPE_AGENT);
      hq[2 * ks + 1] = __hip_atomic_load((const unsigned long long*)(ap + 4),
                                         __ATOMIC_RELAXED, __HIP_MEMORY_SCOPE_AGENT);
    }

    floatx4 ah0 = {0.f,0.f,0.f,0.f}, ah1 = {0.f,0.f,0.f,0.f};
    #pragma unroll
    for (int ks = 0; ks < 32; ++ks) {
      int koff = DD + ks * 32 + kq;
      bf16x8 b = *(const bf16x8*)&wlds[lcol * KTOT + (koff ^ ((lcol & 7) * 8))];
      union { unsigned long long q[2]; bf16x8 v; } u;
      u.q[0] = hq[2 * ks]; u.q[1] = hq[2 * ks + 1];
      if (ks & 1) ah1 = __builtin_amdgcn_mfma_f32_16x16x32_bf16(u.v, b, ah1, 0, 0, 0);
      else        ah0 = __builtin_amdgcn_mfma_f32_16x16x32_bf16(u.v, b, ah0, 0, 0, 0);
    }

    // ---- epilogue: shuffle-combine 4 gates; gate==0 lanes finalize
    unsigned short* hnext = hb + ((t + 1) & 1) * BH;
    #pragma unroll
    for (int r = 0; r < 4; ++r) {
      float v = ax0[r] + ax1[r] + ah0[r] + ah1[r] + bias;
      float v4  = __shfl_xor(v, 4);
      float v8  = __shfl_xor(v, 8);
      float v12 = __shfl_xor(v, 12);
      if (gate == 0) {
        int row = row_e + r;
        float fv = sigmoid_(v);
        float iv = sigmoid_(v4);
        float gv = tanhf(v8);
        float ov = sigmoid_(v12);
        float cn = fv * creg[r] + iv * gv;
        float hn = ov * tanhf(cn);
        creg[r] = cn;
        int idx = row * HH + col_e;
        __hip_atomic_store(&hnext[idx], f2bf(hn),
                           __ATOMIC_RELAXED, __HIP_MEMORY_SCOPE_AGENT);
        out[(size_t)t * BH + idx] = hn;
        if (t == TT - 1) { out[TBH + idx] = hn; out[TBH + BH + idx] = cn; }
      }
    }

    if (t < TT - 1) {
      asm volatile("s_waitcnt vmcnt(0)" ::: "memory");   // h stores at LLC
      __syncthreads();                                   // all waves drained
      if (tid == 0)
        __hip_atomic_store(&flags[wg * 16], t + 2,
                           __ATOMIC_RELAXED, __HIP_MEMORY_SCOPE_AGENT);
    }
  }
}

extern "C" void kernel_launch(void* const* d_in, const int* in_sizes, int n_in,
                              void* d_out, int out_size, void* d_ws, size_t ws_size,
                              hipStream_t stream) {
  (void)in_sizes; (void)n_in; (void)out_size;
  const float* x   = (const float*)d_in[0];
  const float* Wf  = (const float*)d_in[1];
  const float* bfp = (const float*)d_in[2];
  const float* Wi  = (const float*)d_in[3];
  const float* bip = (const float*)d_in[4];
  const float* Wg  = (const float*)d_in[5];
  const float* bgp = (const float*)d_in[6];
  const float* Wo  = (const float*)d_in[7];
  const float* bop = (const float*)d_in[8];
  float* out = (float*)d_out;

  unsigned short* hb  = (unsigned short*)d_ws;                    // 256 KB
  int* flags          = (int*)((char*)d_ws + 262144);             // 16 KB
  unsigned short* xbf = (unsigned short*)((char*)d_ws + 524288);  // 33.5 MB opt

  size_t need = 524288ULL + (size_t)TT * BB * DD * 2;
  int use_xbf = (ws_size >= need) ? 1 : 0;
  if (use_xbf) {
    cvt_x_kernel<<<1024, 256, 0, stream>>>(x, xbf, TT * BB * DD);
  }

  void* args[] = { (void*)&x, (void*)&Wf, (void*)&bfp, (void*)&Wi, (void*)&bip,
                   (void*)&Wg, (void*)&bgp, (void*)&Wo, (void*)&bop,
                   (void*)&out, (void*)&hb, (void*)&flags, (void*)&xbf, (void*)&use_xbf };
  hipLaunchCooperativeKernel((void*)lstm_rec, dim3(NWG), dim3(256),
                             args, 65536, stream);
}